// Round 1
// baseline (826.983 us; speedup 1.0000x reference)
//
#include <hip/hip_runtime.h>
#include <hip/hip_bf16.h>

// GCN 2-layer: out = (Â relu(Â (x@W1) + b1)) @ W2 + b2  with Â = D^-1/2 (A+I) D^-1/2
// N=100000 nodes, E=3200000 edges, dims 128 -> 32 -> 16, all fp32.

#define IN_DIM 128
#define HID1 32
#define HID2 16

// ---------------------------------------------------------------------------
// Edge dtype probe: reference declares int64, but default-JAX yields int32.
// If the buffer is int64 (little-endian), every odd 32-bit word of the first
// 64 entries is 0 (values < 2^31). Random int32 node ids make that impossible.
__global__ void detect_fmt(const int* __restrict__ e32, int* __restrict__ flag) {
    if (blockIdx.x == 0 && threadIdx.x == 0) {
        int is64 = 1;
        for (int i = 0; i < 64; ++i) {
            if (e32[2 * i + 1] != 0) { is64 = 0; break; }
        }
        *flag = is64;
    }
}

__device__ __forceinline__ void load_edge(const int* __restrict__ e32, int is64,
                                          long e, long E, int& s, int& d) {
    if (is64) {
        s = e32[2 * e];
        d = e32[2 * E + 2 * e];
    } else {
        s = e32[e];
        d = e32[E + e];
    }
}

// ---------------------------------------------------------------------------
__global__ void init_deg(float* __restrict__ deg, int N) {
    int i = blockIdx.x * blockDim.x + threadIdx.x;
    if (i < N) deg[i] = 1.0f;  // self loop
}

__global__ void count_deg(const int* __restrict__ e32, const int* __restrict__ flag,
                          float* __restrict__ deg, int E) {
    int is64 = *flag;
    long stride = (long)gridDim.x * blockDim.x;
    for (long e = blockIdx.x * (long)blockDim.x + threadIdx.x; e < E; e += stride) {
        int s, d;
        load_edge(e32, is64, e, E, s, d);
        atomicAdd(&deg[d], 1.0f);
    }
}

__global__ void make_inv(float* __restrict__ deg, int N) {
    int i = blockIdx.x * blockDim.x + threadIdx.x;
    if (i < N) deg[i] = rsqrtf(deg[i]);  // deg >= 1 always (self loops)
}

// ---------------------------------------------------------------------------
// xw = x @ W1   (x: [N,128], W1: [128,32])
__global__ __launch_bounds__(256) void gemm1(const float* __restrict__ x,
                                             const float* __restrict__ W1,
                                             float* __restrict__ xw, int N) {
    __shared__ float sW[IN_DIM * HID1];  // 16 KB
    __shared__ float sX[8 * IN_DIM];     // 4 KB
    for (int i = threadIdx.x; i < IN_DIM * HID1 / 4; i += 256)
        ((float4*)sW)[i] = ((const float4*)W1)[i];

    int row0 = blockIdx.x * 8;
    {
        int rr = threadIdx.x / 32;
        int kk = (threadIdx.x % 32) * 4;
        int grow = row0 + rr;
        float4 v = make_float4(0.f, 0.f, 0.f, 0.f);
        if (grow < N) v = *(const float4*)&x[(size_t)grow * IN_DIM + kk];
        *(float4*)&sX[rr * IN_DIM + kk] = v;
    }
    __syncthreads();

    int col = threadIdx.x % HID1;
    int lr  = threadIdx.x / HID1;
    int grow = row0 + lr;
    if (grow >= N) return;
    float acc = 0.f;
#pragma unroll
    for (int k = 0; k < IN_DIM; ++k)
        acc += sX[lr * IN_DIM + k] * sW[k * HID1 + col];
    xw[(size_t)grow * HID1 + col] = acc;
}

// agg1[n][c] = b1[c] + xw[n][c] * inv[n]^2   (self-loop + bias folded in)
__global__ void init_agg1(const float* __restrict__ xw, const float* __restrict__ inv,
                          const float* __restrict__ b1, float* __restrict__ agg1, int N) {
    long i = blockIdx.x * (long)blockDim.x + threadIdx.x;
    long total = (long)N * HID1;
    if (i >= total) return;
    int n = (int)(i / HID1);
    int c = (int)(i % HID1);
    float iv = inv[n];
    agg1[i] = b1[c] + xw[i] * iv * iv;
}

// scatter layer 1: 32 lanes per edge, one channel per lane
__global__ __launch_bounds__(256) void scatter1(const int* __restrict__ e32,
                                                const int* __restrict__ flag,
                                                const float* __restrict__ inv,
                                                const float* __restrict__ xw,
                                                float* __restrict__ agg1, int E) {
    int is64 = *flag;
    int lane = threadIdx.x % HID1;
    long e = blockIdx.x * (long)(blockDim.x / HID1) + threadIdx.x / HID1;
    if (e >= E) return;
    int s, d;
    load_edge(e32, is64, e, E, s, d);
    float w = inv[s] * inv[d];
    float v = xw[(size_t)s * HID1 + lane] * w;
    atomicAdd(&agg1[(size_t)d * HID1 + lane], v);
}

// hw = relu(agg1) @ W2   (agg1: [N,32], W2: [32,16])
__global__ __launch_bounds__(256) void gemm2(const float* __restrict__ h,
                                             const float* __restrict__ W2,
                                             float* __restrict__ hw, int N) {
    __shared__ float sW[HID1 * HID2];  // 2 KB
    for (int i = threadIdx.x; i < HID1 * HID2; i += 256) sW[i] = W2[i];
    __syncthreads();

    int col = threadIdx.x % HID2;
    int lr  = threadIdx.x / HID2;  // 16 rows per block
    int grow = blockIdx.x * 16 + lr;
    if (grow >= N) return;
    float acc = 0.f;
#pragma unroll
    for (int c = 0; c < HID1; ++c) {
        float v = h[(size_t)grow * HID1 + c];
        v = fmaxf(v, 0.f);
        acc += v * sW[c * HID2 + col];
    }
    hw[(size_t)grow * HID2 + col] = acc;
}

// out[n][j] = b2[j] + hw[n][j] * inv[n]^2
__global__ void init_out(const float* __restrict__ hw, const float* __restrict__ inv,
                         const float* __restrict__ b2, float* __restrict__ out, int N) {
    long i = blockIdx.x * (long)blockDim.x + threadIdx.x;
    long total = (long)N * HID2;
    if (i >= total) return;
    int n = (int)(i / HID2);
    int c = (int)(i % HID2);
    float iv = inv[n];
    out[i] = b2[c] + hw[i] * iv * iv;
}

// scatter layer 2: 16 lanes per edge
__global__ __launch_bounds__(256) void scatter2(const int* __restrict__ e32,
                                                const int* __restrict__ flag,
                                                const float* __restrict__ inv,
                                                const float* __restrict__ hw,
                                                float* __restrict__ out, int E) {
    int is64 = *flag;
    int lane = threadIdx.x % HID2;
    long e = blockIdx.x * (long)(blockDim.x / HID2) + threadIdx.x / HID2;
    if (e >= E) return;
    int s, d;
    load_edge(e32, is64, e, E, s, d);
    float w = inv[s] * inv[d];
    float v = hw[(size_t)s * HID2 + lane] * w;
    atomicAdd(&out[(size_t)d * HID2 + lane], v);
}

// ---------------------------------------------------------------------------
extern "C" void kernel_launch(void* const* d_in, const int* in_sizes, int n_in,
                              void* d_out, int out_size, void* d_ws, size_t ws_size,
                              hipStream_t stream) {
    const float* x  = (const float*)d_in[0];
    const float* W1 = (const float*)d_in[1];
    const float* b1 = (const float*)d_in[2];
    const float* W2 = (const float*)d_in[3];
    const float* b2 = (const float*)d_in[4];
    const int*  e32 = (const int*)d_in[5];
    float* out = (float*)d_out;

    const int N = in_sizes[0] / IN_DIM;   // 100000
    const int E = in_sizes[5] / 2;        // 3200000

    // workspace layout (fp32 elements), total ~26 MB
    char* ws = (char*)d_ws;
    int*   flag = (int*)ws;
    float* inv  = (float*)(ws + 256);             // N floats (deg -> inv_sqrt in place)
    float* xw   = inv + ((N + 63) / 64) * 64;     // N*32 floats; reused as hw later
    float* agg1 = xw + (size_t)N * HID1;          // N*32 floats
    float* hw   = xw;                             // safe: xw dead after scatter1

    detect_fmt<<<1, 64, 0, stream>>>(e32, flag);

    init_deg<<<(N + 255) / 256, 256, 0, stream>>>(inv, N);
    count_deg<<<(E + 255) / 256, 256, 0, stream>>>(e32, flag, inv, E);
    make_inv<<<(N + 255) / 256, 256, 0, stream>>>(inv, N);

    gemm1<<<(N + 7) / 8, 256, 0, stream>>>(x, W1, xw, N);
    init_agg1<<<(int)(((long)N * HID1 + 255) / 256), 256, 0, stream>>>(xw, inv, b1, agg1, N);
    scatter1<<<(int)(((long)E * HID1 + 255) / 256), 256, 0, stream>>>(e32, flag, inv, xw, agg1, E);

    gemm2<<<(N + 15) / 16, 256, 0, stream>>>(agg1, W2, hw, N);
    init_out<<<(int)(((long)N * HID2 + 255) / 256), 256, 0, stream>>>(hw, inv, b2, out, N);
    scatter2<<<(int)(((long)E * HID2 + 255) / 256), 256, 0, stream>>>(e32, flag, inv, hw, out, E);
}

// Round 2
// 804.683 us; speedup vs baseline: 1.0277x; 1.0277x over previous
//
#include <hip/hip_runtime.h>
#include <hip/hip_bf16.h>

// GCN 2-layer: out = (Â relu(Â (x@W1) + b1)) @ W2 + b2,  Â = D^-1/2 (A+I) D^-1/2
// N=100000, E=3200000, dims 128 -> 32 -> 16, fp32.
// Round 2: CSR-by-destination + per-wave gather aggregation (no fp32 atomics).

#define IN_DIM 128
#define HID1 32
#define HID2 16

// ---------------------------------------------------------------------------
// Edge dtype probe (reference says int64; default JAX gives int32).
__global__ void detect_fmt(const int* __restrict__ e32, int* __restrict__ flag) {
    if (blockIdx.x == 0 && threadIdx.x == 0) {
        int is64 = 1;
        for (int i = 0; i < 64; ++i)
            if (e32[2 * i + 1] != 0) { is64 = 0; break; }
        *flag = is64;
    }
}

__device__ __forceinline__ void load_edge(const int* __restrict__ e32, int is64,
                                          long e, long E, int& s, int& d) {
    if (is64) { s = e32[2 * e];  d = e32[2 * E + 2 * e]; }
    else      { s = e32[e];      d = e32[E + e]; }
}

// ---------------------------------------------------------------------------
__global__ void zero_cnt(int* __restrict__ cnt, int* __restrict__ total, int N) {
    int i = blockIdx.x * blockDim.x + threadIdx.x;
    if (i < N) cnt[i] = 0;
    if (i == 0) *total = 0;
}

__global__ void count_dst(const int* __restrict__ e32, const int* __restrict__ flag,
                          int* __restrict__ cnt, int E) {
    int is64 = *flag;
    long e = blockIdx.x * (long)blockDim.x + threadIdx.x;
    if (e >= E) return;
    int s, d;
    load_edge(e32, is64, e, E, s, d);
    atomicAdd(&cnt[d], 1);
}

// rowStart[n] = segment alloc (order irrelevant); cursor=rowStart; inv = rsqrt(deg+1)
__global__ void alloc_rows(const int* __restrict__ cnt, int* __restrict__ total,
                           int* __restrict__ rowStart, int* __restrict__ cursor,
                           float* __restrict__ inv, int N) {
    int n = blockIdx.x * blockDim.x + threadIdx.x;
    if (n >= N) return;
    int c = cnt[n];
    int rs = atomicAdd(total, c);   // wave-aggregated by the compiler
    rowStart[n] = rs;
    cursor[n]   = rs;
    inv[n]      = rsqrtf((float)(c + 1));
}

__global__ void fill_csr(const int* __restrict__ e32, const int* __restrict__ flag,
                         int* __restrict__ cursor, int* __restrict__ srcs, int E) {
    int is64 = *flag;
    long e = blockIdx.x * (long)blockDim.x + threadIdx.x;
    if (e >= E) return;
    int s, d;
    load_edge(e32, is64, e, E, s, d);
    int pos = atomicAdd(&cursor[d], 1);
    srcs[pos] = s;
}

// ---------------------------------------------------------------------------
// xw = x @ W1   (x: [N,128], W1: [128,32])
__global__ __launch_bounds__(256) void gemm1(const float* __restrict__ x,
                                             const float* __restrict__ W1,
                                             float* __restrict__ xw, int N) {
    __shared__ float sW[IN_DIM * HID1];  // 16 KB
    __shared__ float sX[8 * IN_DIM];     // 4 KB
    for (int i = threadIdx.x; i < IN_DIM * HID1 / 4; i += 256)
        ((float4*)sW)[i] = ((const float4*)W1)[i];

    int row0 = blockIdx.x * 8;
    {
        int rr = threadIdx.x / 32;
        int kk = (threadIdx.x % 32) * 4;
        int grow = row0 + rr;
        float4 v = make_float4(0.f, 0.f, 0.f, 0.f);
        if (grow < N) v = *(const float4*)&x[(size_t)grow * IN_DIM + kk];
        *(float4*)&sX[rr * IN_DIM + kk] = v;
    }
    __syncthreads();

    int col = threadIdx.x % HID1;
    int lr  = threadIdx.x / HID1;
    int grow = row0 + lr;
    if (grow >= N) return;
    float acc = 0.f;
#pragma unroll
    for (int k = 0; k < IN_DIM; ++k)
        acc += sX[lr * IN_DIM + k] * sW[k * HID1 + col];
    xw[(size_t)grow * HID1 + col] = acc;
}

// ---------------------------------------------------------------------------
// Layer-1 aggregate: one 64-lane wave per node; 2 edges x 32 channels / iter.
// agg1[n][c] = relu( b1[c] + inv[n] * ( xw[n][c]*inv[n] + Σ_e xw[s][c]*inv[s] ) )
__global__ __launch_bounds__(256) void agg1_k(const int* __restrict__ rowStart,
                                              const int* __restrict__ cnt,
                                              const int* __restrict__ srcs,
                                              const float* __restrict__ inv,
                                              const float* __restrict__ xw,
                                              const float* __restrict__ b1,
                                              float* __restrict__ agg1, int N) {
    int wave = (blockIdx.x * blockDim.x + threadIdx.x) >> 6;
    int lane = threadIdx.x & 63;
    if (wave >= N) return;
    int n = wave;
    int c    = lane & 31;
    int half = lane >> 5;          // 0 or 1
    int start = rowStart[n];
    int len   = cnt[n];
    float invn = inv[n];
    float acc = (half == 0) ? xw[(size_t)n * HID1 + c] * invn : 0.f;
    for (int j = half; j < len; j += 2) {
        int s = srcs[start + j];
        acc += xw[(size_t)s * HID1 + c] * inv[s];
    }
    acc += __shfl_down(acc, 32, 64);   // fold half 1 into half 0
    if (half == 0) {
        float v = b1[c] + invn * acc;
        agg1[(size_t)n * HID1 + c] = fmaxf(v, 0.f);   // ReLU folded
    }
}

// hw = agg1 @ W2   (agg1 already ReLU'd; [N,32] @ [32,16])
__global__ __launch_bounds__(256) void gemm2(const float* __restrict__ h,
                                             const float* __restrict__ W2,
                                             float* __restrict__ hw, int N) {
    __shared__ float sW[HID1 * HID2];  // 2 KB
    for (int i = threadIdx.x; i < HID1 * HID2; i += 256) sW[i] = W2[i];
    __syncthreads();

    int col = threadIdx.x % HID2;
    int lr  = threadIdx.x / HID2;  // 16 rows per block
    int grow = blockIdx.x * 16 + lr;
    if (grow >= N) return;
    float acc = 0.f;
#pragma unroll
    for (int c = 0; c < HID1; ++c)
        acc += h[(size_t)grow * HID1 + c] * sW[c * HID2 + col];
    hw[(size_t)grow * HID2 + col] = acc;
}

// Layer-2 aggregate: one wave per node; 4 edges x 16 channels / iter.
__global__ __launch_bounds__(256) void agg2_k(const int* __restrict__ rowStart,
                                              const int* __restrict__ cnt,
                                              const int* __restrict__ srcs,
                                              const float* __restrict__ inv,
                                              const float* __restrict__ hw,
                                              const float* __restrict__ b2,
                                              float* __restrict__ out, int N) {
    int wave = (blockIdx.x * blockDim.x + threadIdx.x) >> 6;
    int lane = threadIdx.x & 63;
    if (wave >= N) return;
    int n = wave;
    int c = lane & 15;
    int q = lane >> 4;             // 0..3
    int start = rowStart[n];
    int len   = cnt[n];
    float invn = inv[n];
    float acc = (q == 0) ? hw[(size_t)n * HID2 + c] * invn : 0.f;
    for (int j = q; j < len; j += 4) {
        int s = srcs[start + j];
        acc += hw[(size_t)s * HID2 + c] * inv[s];
    }
    acc += __shfl_down(acc, 32, 64);   // q0+=q2, q1+=q3
    acc += __shfl_down(acc, 16, 64);   // q0+=q1
    if (q == 0)
        out[(size_t)n * HID2 + c] = b2[c] + invn * acc;
}

// ---------------------------------------------------------------------------
extern "C" void kernel_launch(void* const* d_in, const int* in_sizes, int n_in,
                              void* d_out, int out_size, void* d_ws, size_t ws_size,
                              hipStream_t stream) {
    const float* x  = (const float*)d_in[0];
    const float* W1 = (const float*)d_in[1];
    const float* b1 = (const float*)d_in[2];
    const float* W2 = (const float*)d_in[3];
    const float* b2 = (const float*)d_in[4];
    const int*  e32 = (const int*)d_in[5];
    float* out = (float*)d_out;

    const int N = in_sizes[0] / IN_DIM;   // 100000
    const int E = in_sizes[5] / 2;        // 3200000
    const int Npad = ((N + 63) / 64) * 64;

    // workspace layout
    char* ws = (char*)d_ws;
    int*   flag     = (int*)ws;                       // 1
    int*   total    = (int*)(ws + 256);               // 1
    int*   cnt      = (int*)(ws + 512);               // N
    int*   rowStart = cnt + Npad;                     // N
    int*   cursor   = rowStart + Npad;                // N
    float* inv      = (float*)(cursor + Npad);        // N
    int*   srcs     = (int*)(inv + Npad);             // E
    float* xw       = (float*)(srcs + ((E + 63) / 64) * 64);  // N*32
    float* agg1     = xw + (size_t)N * HID1;          // N*32
    float* hw       = xw;                             // alias: xw dead after agg1

    detect_fmt<<<1, 64, 0, stream>>>(e32, flag);

    zero_cnt<<<(N + 255) / 256, 256, 0, stream>>>(cnt, total, N);
    count_dst<<<(E + 255) / 256, 256, 0, stream>>>(e32, flag, cnt, E);
    alloc_rows<<<(N + 255) / 256, 256, 0, stream>>>(cnt, total, rowStart, cursor, inv, N);
    fill_csr<<<(E + 255) / 256, 256, 0, stream>>>(e32, flag, cursor, srcs, E);

    gemm1<<<(N + 7) / 8, 256, 0, stream>>>(x, W1, xw, N);
    agg1_k<<<(N + 3) / 4, 256, 0, stream>>>(rowStart, cnt, srcs, inv, xw, b1, agg1, N);

    gemm2<<<(N + 15) / 16, 256, 0, stream>>>(agg1, W2, hw, N);
    agg2_k<<<(N + 3) / 4, 256, 0, stream>>>(rowStart, cnt, srcs, inv, hw, b2, out, N);
}